// Round 1
// baseline (472.259 us; speedup 1.0000x reference)
//
#include <hip/hip_runtime.h>

typedef unsigned short ushort_t;
typedef __attribute__((ext_vector_type(8))) short short8;
typedef __attribute__((ext_vector_type(4))) float f32x4;

#define MFMA_BF16(a, b, c) __builtin_amdgcn_mfma_f32_16x16x32_bf16((a), (b), (c), 0, 0, 0)

#define T_LEN 1024
#define BATCH 4
#define NHEAD 16
#define DHEAD 64
#define EMB 1024

__device__ __forceinline__ ushort_t f2bf(float f) {
  unsigned u = __float_as_uint(f);
  u += 0x7fffu + ((u >> 16) & 1u);
  return (ushort_t)(u >> 16);
}

// ---------------- elementwise ----------------
__global__ void sample_bf16_kernel(const float* __restrict__ mu, const float* __restrict__ rho,
                                   const float* __restrict__ eps, ushort_t* __restrict__ out, int n) {
  int i = blockIdx.x * 256 + threadIdx.x;
  if (i < n) {
    float sp = log1pf(__expf(rho[i]));
    out[i] = f2bf(mu[i] + sp * eps[i]);
  }
}

__global__ void sample_f32_kernel(const float* __restrict__ mu, const float* __restrict__ rho,
                                  const float* __restrict__ eps, float* __restrict__ out, int n) {
  int i = blockIdx.x * 256 + threadIdx.x;
  if (i < n) {
    float sp = log1pf(__expf(rho[i]));
    out[i] = mu[i] + sp * eps[i];
  }
}

__global__ void cast_bf16_kernel(const float* __restrict__ in, ushort_t* __restrict__ out, int n) {
  int i = blockIdx.x * 256 + threadIdx.x;
  if (i < n) out[i] = f2bf(in[i]);
}

// ---------------- GEMM: C[M][N] = A[M][K] * Bt[N][K]^T + bias[N] ----------------
// 128x128 tile, BK=32, 4 waves (2x2), each wave 64x64 = 4x4 MFMA 16x16x32 frags.
__global__ __launch_bounds__(256, 2)
void gemm_bt_kernel(const ushort_t* __restrict__ A, const ushort_t* __restrict__ Bt,
                    const float* __restrict__ bias, float* __restrict__ C,
                    int M, int N, int K) {
  __shared__ ushort_t As[128 * 32];
  __shared__ ushort_t Bs[128 * 32];
  const int tid = threadIdx.x;
  const int w = tid >> 6, l = tid & 63;
  const int m0 = blockIdx.x * 128, n0 = blockIdx.y * 128;
  const int wr = w >> 1, wc = w & 1;
  const int fr = l & 15, fk = (l >> 4) * 8;

  f32x4 acc[4][4] = {};

  for (int k0 = 0; k0 < K; k0 += 32) {
    __syncthreads();
#pragma unroll
    for (int p = 0; p < 2; ++p) {
      int c = p * 256 + tid;           // 16B chunk id, 512 total per tile
      int row = c >> 2, col = (c & 3) * 8;
      *(short8*)(&As[c * 8]) = *(const short8*)(&A[(size_t)(m0 + row) * K + k0 + col]);
      *(short8*)(&Bs[c * 8]) = *(const short8*)(&Bt[(size_t)(n0 + row) * K + k0 + col]);
    }
    __syncthreads();
    short8 af[4], bf[4];
#pragma unroll
    for (int mi = 0; mi < 4; ++mi) af[mi] = *(const short8*)(&As[(wr * 64 + mi * 16 + fr) * 32 + fk]);
#pragma unroll
    for (int ni = 0; ni < 4; ++ni) bf[ni] = *(const short8*)(&Bs[(wc * 64 + ni * 16 + fr) * 32 + fk]);
#pragma unroll
    for (int mi = 0; mi < 4; ++mi)
#pragma unroll
      for (int ni = 0; ni < 4; ++ni)
        acc[mi][ni] = MFMA_BF16(af[mi], bf[ni], acc[mi][ni]);
  }

#pragma unroll
  for (int ni = 0; ni < 4; ++ni) {
    int col = n0 + wc * 64 + ni * 16 + fr;
    float bv = bias[col];
#pragma unroll
    for (int mi = 0; mi < 4; ++mi) {
#pragma unroll
      for (int q = 0; q < 4; ++q) {
        int row = m0 + wr * 64 + mi * 16 + (l >> 4) * 4 + q;
        C[(size_t)row * N + col] = acc[mi][ni][q] + bv;
      }
    }
  }
}

// ---------------- prep: split qkv, add rel biases, per-head layouts ----------------
// qrw/qrr/kb layout: [B][H][T][64]; idx = ((b*16+h)*1024 + t)*64 + dd
__global__ void prep_qkv_kernel(const float* __restrict__ qkv, const float* __restrict__ rwb,
                                const float* __restrict__ rrb,
                                ushort_t* __restrict__ qrw, ushort_t* __restrict__ qrr,
                                ushort_t* __restrict__ kb) {
  int idx = blockIdx.x * 256 + threadIdx.x;
  if (idx >= BATCH * NHEAD * T_LEN * DHEAD) return;
  int dd = idx & 63;
  int t = (idx >> 6) & 1023;
  int h = (idx >> 16) & 15;
  int b = idx >> 20;
  size_t src = (size_t)(t * BATCH + b) * (3 * EMB) + h * 64 + dd;
  float qv = qkv[src];
  float kv = qkv[src + EMB];
  qrw[idx] = f2bf(qv + rwb[h * 64 + dd]);
  qrr[idx] = f2bf(qv + rrb[h * 64 + dd]);
  kb[idx] = f2bf(kv);
}

// vt layout: [B][H][64][T] (V transposed per head)
__global__ void prep_vt_kernel(const float* __restrict__ qkv, ushort_t* __restrict__ vt) {
  __shared__ ushort_t tile[64][65];
  int bh = blockIdx.y;
  int b = bh >> 4, h = bh & 15;
  int t0 = blockIdx.x * 64;
  for (int i = threadIdx.x; i < 64 * 64; i += 256) {
    int r = i >> 6, c = i & 63;
    tile[r][c] = f2bf(qkv[(size_t)((t0 + r) * BATCH + b) * (3 * EMB) + 2 * EMB + h * 64 + c]);
  }
  __syncthreads();
  for (int i = threadIdx.x; i < 64 * 64; i += 256) {
    int dr = i >> 6, tc = i & 63;
    vt[(size_t)(bh * 64 + dr) * T_LEN + t0 + tc] = tile[tc][dr];
  }
}

// rhp layout: [H][1152][64], rows 0..63 and 1088..1151 are zero pad; row 64+t = r[t]
__global__ void prep_rhp_kernel(const float* __restrict__ r_f, ushort_t* __restrict__ rhp) {
  int idx = blockIdx.x * 256 + threadIdx.x;
  if (idx >= NHEAD * 1152 * 64) return;
  int dd = idx & 63;
  int r6 = idx >> 6;
  int row = r6 % 1152;
  int h = r6 / 1152;
  int t = row - 64;
  ushort_t v = 0;
  if (t >= 0 && t < T_LEN) v = f2bf(r_f[(size_t)t * EMB + h * 64 + dd]);
  rhp[idx] = v;
}

// ---------------- fused rel-shift attention ----------------
// Block: (qtile of 32 rows) x (b,h). 4 waves. S strip [32][1024] f32 in LDS (XOR swizzled).
__global__ __launch_bounds__(256, 2)
void attn_kernel(const ushort_t* __restrict__ qrw, const ushort_t* __restrict__ qrr,
                 const ushort_t* __restrict__ kb, const ushort_t* __restrict__ vt,
                 const ushort_t* __restrict__ rhp, ushort_t* __restrict__ ctx) {
  extern __shared__ __attribute__((aligned(16))) char smem[];
  float* mrow = (float*)(smem + 131072);
  float* srow = mrow + 32;
  const int tid = threadIdx.x, w = tid >> 6, l = tid & 63;
  const int bh = blockIdx.y, b = bh >> 4, h = bh & 15;
  const int i0 = blockIdx.x * 32;
  const int nkt = (i0 + 95) >> 6;     // number of 64-wide key tiles needed (causal)
  const int fr = l & 15, fkq = (l >> 4) * 8;
  const int istrip_loc = 16 * (w & 1);
  const int istrip = i0 + istrip_loc;
  const int whalf = (w >> 1) * 32;
  const float scale = 0.125f;

  // Q fragments held in registers for the whole block
  short8 aqw[2], aqr[2];
  {
    size_t qb = ((size_t)bh * T_LEN + istrip + fr) * 64 + fkq;
    aqw[0] = *(const short8*)(qrw + qb);
    aqw[1] = *(const short8*)(qrw + qb + 32);
    aqr[0] = *(const short8*)(qrr + qb);
    aqr[1] = *(const short8*)(qrr + qb + 32);
  }

  // ---- score phase: S[rloc][j] = scale*(AC+BD), masked ----
  for (int jt = 0; jt < nkt; ++jt) {
    const int j0 = jt * 64;
    const int jc = j0 + whalf;
    f32x4 ac0 = {0, 0, 0, 0}, ac1 = {0, 0, 0, 0};
    {
      size_t kb0 = ((size_t)bh * T_LEN + jc + fr) * 64 + fkq;
      short8 b0 = *(const short8*)(kb + kb0);
      short8 b1 = *(const short8*)(kb + kb0 + 32);
      ac0 = MFMA_BF16(aqw[0], b0, ac0);
      ac0 = MFMA_BF16(aqw[1], b1, ac0);
      size_t kb1 = kb0 + (size_t)16 * 64;
      short8 b2 = *(const short8*)(kb + kb1);
      short8 b3 = *(const short8*)(kb + kb1 + 32);
      ac1 = MFMA_BF16(aqw[0], b2, ac1);
      ac1 = MFMA_BF16(aqw[1], b3, ac1);
    }
    // BD band P[16][48], band base jr0 (logical r index); phys row = 64 + jr0 + colp
    f32x4 pb0 = {0, 0, 0, 0}, pb1 = {0, 0, 0, 0}, pb2 = {0, 0, 0, 0};
    const int jr0 = T_LEN - 16 - istrip + jc;
    {
      size_t rb = ((size_t)h * 1152 + 64 + jr0 + fr) * 64 + fkq;
      short8 r0 = *(const short8*)(rhp + rb);
      short8 r1 = *(const short8*)(rhp + rb + 32);
      pb0 = MFMA_BF16(aqr[0], r0, pb0);
      pb0 = MFMA_BF16(aqr[1], r1, pb0);
      size_t rb1 = rb + (size_t)16 * 64;
      short8 r2 = *(const short8*)(rhp + rb1);
      short8 r3 = *(const short8*)(rhp + rb1 + 32);
      pb1 = MFMA_BF16(aqr[0], r2, pb1);
      pb1 = MFMA_BF16(aqr[1], r3, pb1);
      size_t rb2 = rb + (size_t)32 * 64;
      short8 r4 = *(const short8*)(rhp + rb2);
      short8 r5 = *(const short8*)(rhp + rb2 + 32);
      pb2 = MFMA_BF16(aqr[0], r4, pb2);
      pb2 = MFMA_BF16(aqr[1], r5, pb2);
    }
    // combine AC + shifted BD, write to LDS
#pragma unroll
    for (int ni = 0; ni < 2; ++ni) {
#pragma unroll
      for (int q = 0; q < 4; ++q) {
        int ri = 4 * (l >> 4) + q;
        int colp = 15 - ri + ni * 16 + fr;       // band col, in [0,46]
        int src = (l & 48) | (colp & 15);
        float v0, v1;
        if (ni == 0) {
          v0 = __shfl(pb0[q], src, 64);
          v1 = __shfl(pb1[q], src, 64);
        } else {
          v0 = __shfl(pb1[q], src, 64);
          v1 = __shfl(pb2[q], src, 64);
        }
        float pv = ((colp >> 4) == ni) ? v0 : v1;
        float accv = (ni == 0) ? ac0[q] : ac1[q];
        float s = (accv + pv) * scale;
        int ig = istrip + ri;
        int jg = jc + ni * 16 + fr;
        if (jg > ig) s = -1e9f;
        int rloc = istrip_loc + ri;
        *(float*)(smem + (((rloc * 4096) + jg * 4) ^ ((rloc & 7) << 4))) = s;
      }
    }
  }
  __syncthreads();

  // ---- softmax stats: rowmax + rowsum ----
  const int ncols = nkt * 64;
  for (int rr = 0; rr < 8; ++rr) {
    int r = w * 8 + rr;
    float m = -3.0e38f;
    for (int j = l; j < ncols; j += 64)
      m = fmaxf(m, *(float*)(smem + (((r * 4096) + j * 4) ^ ((r & 7) << 4))));
#pragma unroll
    for (int o = 32; o; o >>= 1) m = fmaxf(m, __shfl_xor(m, o, 64));
    float sum = 0.f;
    for (int j = l; j < ncols; j += 64)
      sum += __expf(*(float*)(smem + (((r * 4096) + j * 4) ^ ((r & 7) << 4))) - m);
#pragma unroll
    for (int o = 32; o; o >>= 1) sum += __shfl_xor(sum, o, 64);
    if (l == 0) { mrow[r] = m; srow[r] = sum; }
  }
  __syncthreads();

  // ---- PV: ctx strip [16][32] per wave ----
  const int mr = w & 1;
  const int d0 = (w >> 1) * 32;
  const int arow = mr * 16 + fr;           // A-frag row (local)
  const float mloc = mrow[arow];
  f32x4 o0 = {0, 0, 0, 0}, o1 = {0, 0, 0, 0};
  const int nkk = nkt * 2;
  for (int kt = 0; kt < nkk; ++kt) {
    int colb = kt * 32 + fkq;
    f32x4 s0 = *(f32x4*)(smem + (((arow * 4096) + colb * 4) ^ ((arow & 7) << 4)));
    f32x4 s1 = *(f32x4*)(smem + (((arow * 4096) + colb * 4 + 16) ^ ((arow & 7) << 4)));
    union { ushort_t u[8]; short8 v; } pk;
#pragma unroll
    for (int jj = 0; jj < 4; ++jj) pk.u[jj] = f2bf(__expf(s0[jj] - mloc));
#pragma unroll
    for (int jj = 0; jj < 4; ++jj) pk.u[4 + jj] = f2bf(__expf(s1[jj] - mloc));
    size_t vb = ((size_t)bh * 64 + d0 + fr) * T_LEN + colb;
    short8 v0 = *(const short8*)(vt + vb);
    short8 v1 = *(const short8*)(vt + vb + (size_t)16 * T_LEN);
    o0 = MFMA_BF16(pk.v, v0, o0);
    o1 = MFMA_BF16(pk.v, v1, o1);
  }
  // write ctx: [T][B][E] bf16
#pragma unroll
  for (int ni = 0; ni < 2; ++ni) {
#pragma unroll
    for (int q = 0; q < 4; ++q) {
      int rloc = mr * 16 + 4 * (l >> 4) + q;
      int ig = i0 + rloc;
      int dd = d0 + ni * 16 + fr;
      float val = ((ni == 0) ? o0[q] : o1[q]) / srow[rloc];
      ctx[((size_t)ig * BATCH + b) * EMB + h * 64 + dd] = f2bf(val);
    }
  }
}

// ---------------- launch ----------------
extern "C" void kernel_launch(void* const* d_in, const int* in_sizes, int n_in,
                              void* d_out, int out_size, void* d_ws, size_t ws_size,
                              hipStream_t stream) {
  (void)in_sizes; (void)n_in; (void)out_size; (void)ws_size;
  const float* x = (const float*)d_in[0];
  const float* pos = (const float*)d_in[1];
  // d_in[2] attn_mask: causal triu(k=1) -> computed analytically in attn kernel
  const float* in_w_mu = (const float*)d_in[3];
  const float* in_w_rho = (const float*)d_in[4];
  const float* in_w_eps = (const float*)d_in[5];
  const float* in_b_mu = (const float*)d_in[6];
  const float* in_b_rho = (const float*)d_in[7];
  const float* in_b_eps = (const float*)d_in[8];
  const float* pos_w_mu = (const float*)d_in[9];
  const float* pos_w_rho = (const float*)d_in[10];
  const float* pos_w_eps = (const float*)d_in[11];
  const float* pos_b_mu = (const float*)d_in[12];
  const float* pos_b_rho = (const float*)d_in[13];
  const float* pos_b_eps = (const float*)d_in[14];
  const float* out_w_mu = (const float*)d_in[15];
  const float* out_w_rho = (const float*)d_in[16];
  const float* out_w_eps = (const float*)d_in[17];
  const float* out_b_mu = (const float*)d_in[18];
  const float* out_b_rho = (const float*)d_in[19];
  const float* out_b_eps = (const float*)d_in[20];
  const float* rw_mu = (const float*)d_in[21];
  const float* rw_rho = (const float*)d_in[22];
  const float* rw_eps = (const float*)d_in[23];
  const float* rr_mu = (const float*)d_in[24];
  const float* rr_rho = (const float*)d_in[25];
  const float* rr_eps = (const float*)d_in[26];

  char* ws = (char*)d_ws;
  ushort_t* in_w_bf  = (ushort_t*)(ws + 0);          // 3072x1024 bf16
  ushort_t* pos_w_bf = (ushort_t*)(ws + 6291456);    // 1024x1024 bf16
  ushort_t* out_w_bf = (ushort_t*)(ws + 8388608);    // 1024x1024 bf16
  float* in_b  = (float*)(ws + 10485760);            // 3072
  float* pos_b = (float*)(ws + 10498048);            // 1024
  float* out_b = (float*)(ws + 10502144);            // 1024
  float* rwb   = (float*)(ws + 10506240);            // 1024
  float* rrb   = (float*)(ws + 10510336);            // 1024
  ushort_t* x_bf    = (ushort_t*)(ws + 10514432);    // 4096x1024 bf16
  ushort_t* posx_bf = (ushort_t*)(ws + 18903040);    // 1024x1024 bf16
  float* qkv_f = (float*)(ws + 21000192);            // 4096x3072 f32
  float* r_f   = (float*)(ws + 71331840);            // 1024x1024 f32
  ushort_t* qrw = (ushort_t*)(ws + 75526144);        // [B][H][T][64] bf16
  ushort_t* qrr = (ushort_t*)(ws + 83914752);
  ushort_t* kb  = (ushort_t*)(ws + 92303360);
  ushort_t* vt  = (ushort_t*)(ws + 100691968);       // [B][H][64][T] bf16
  ushort_t* rhp = (ushort_t*)(ws + 109080576);       // [H][1152][64] bf16
  ushort_t* ctx = (ushort_t*)(ws + 21000192);        // alias qkv_f (dead after prep)

  sample_bf16_kernel<<<12288, 256, 0, stream>>>(in_w_mu, in_w_rho, in_w_eps, in_w_bf, 3145728);
  sample_bf16_kernel<<<4096, 256, 0, stream>>>(pos_w_mu, pos_w_rho, pos_w_eps, pos_w_bf, 1048576);
  sample_bf16_kernel<<<4096, 256, 0, stream>>>(out_w_mu, out_w_rho, out_w_eps, out_w_bf, 1048576);
  sample_f32_kernel<<<12, 256, 0, stream>>>(in_b_mu, in_b_rho, in_b_eps, in_b, 3072);
  sample_f32_kernel<<<4, 256, 0, stream>>>(pos_b_mu, pos_b_rho, pos_b_eps, pos_b, 1024);
  sample_f32_kernel<<<4, 256, 0, stream>>>(out_b_mu, out_b_rho, out_b_eps, out_b, 1024);
  sample_f32_kernel<<<4, 256, 0, stream>>>(rw_mu, rw_rho, rw_eps, rwb, 1024);
  sample_f32_kernel<<<4, 256, 0, stream>>>(rr_mu, rr_rho, rr_eps, rrb, 1024);
  cast_bf16_kernel<<<16384, 256, 0, stream>>>(x, x_bf, 4194304);
  cast_bf16_kernel<<<4096, 256, 0, stream>>>(pos, posx_bf, 1048576);

  gemm_bt_kernel<<<dim3(32, 24), 256, 0, stream>>>(x_bf, in_w_bf, in_b, qkv_f, 4096, 3072, 1024);
  gemm_bt_kernel<<<dim3(8, 8), 256, 0, stream>>>(posx_bf, pos_w_bf, pos_b, r_f, 1024, 1024, 1024);

  prep_qkv_kernel<<<16384, 256, 0, stream>>>(qkv_f, rwb, rrb, qrw, qrr, kb);
  prep_vt_kernel<<<dim3(16, 64), 256, 0, stream>>>(qkv_f, vt);
  prep_rhp_kernel<<<4608, 256, 0, stream>>>(r_f, rhp);

  attn_kernel<<<dim3(32, 64), 256, 131328, stream>>>(qrw, qrr, kb, vt, rhp, ctx);

  gemm_bt_kernel<<<dim3(32, 8), 256, 0, stream>>>(ctx, out_w_bf, out_b, (float*)d_out, 4096, 1024, 1024);
}

// Round 2
// 357.379 us; speedup vs baseline: 1.3215x; 1.3215x over previous
//
#include <hip/hip_runtime.h>

typedef unsigned short ushort_t;
typedef __attribute__((ext_vector_type(8))) short short8;
typedef __attribute__((ext_vector_type(4))) float f32x4;

#define MFMA_BF16(a, b, c) __builtin_amdgcn_mfma_f32_16x16x32_bf16((a), (b), (c), 0, 0, 0)

#define T_LEN 1024
#define BATCH 4
#define NHEAD 16
#define DHEAD 64
#define EMB 1024

__device__ __forceinline__ ushort_t f2bf(float f) {
  unsigned u = __float_as_uint(f);
  u += 0x7fffu + ((u >> 16) & 1u);
  return (ushort_t)(u >> 16);
}

// ---------------- elementwise ----------------
__global__ void sample_bf16_kernel(const float* __restrict__ mu, const float* __restrict__ rho,
                                   const float* __restrict__ eps, ushort_t* __restrict__ out, int n) {
  int i = blockIdx.x * 256 + threadIdx.x;
  if (i < n) {
    float sp = log1pf(__expf(rho[i]));
    out[i] = f2bf(mu[i] + sp * eps[i]);
  }
}

__global__ void sample_f32_kernel(const float* __restrict__ mu, const float* __restrict__ rho,
                                  const float* __restrict__ eps, float* __restrict__ out, int n) {
  int i = blockIdx.x * 256 + threadIdx.x;
  if (i < n) {
    float sp = log1pf(__expf(rho[i]));
    out[i] = mu[i] + sp * eps[i];
  }
}

__global__ void cast_bf16_kernel(const float* __restrict__ in, ushort_t* __restrict__ out, int n) {
  int i = blockIdx.x * 256 + threadIdx.x;
  if (i < n) out[i] = f2bf(in[i]);
}

// ---------------- GEMM: C[M][N] = A[M][K] * Bt[N][K]^T + bias[N] ----------------
__global__ __launch_bounds__(256, 2)
void gemm_bt_kernel(const ushort_t* __restrict__ A, const ushort_t* __restrict__ Bt,
                    const float* __restrict__ bias, float* __restrict__ C,
                    int M, int N, int K) {
  __shared__ ushort_t As[128 * 32];
  __shared__ ushort_t Bs[128 * 32];
  const int tid = threadIdx.x;
  const int w = tid >> 6, l = tid & 63;
  const int m0 = blockIdx.x * 128, n0 = blockIdx.y * 128;
  const int wr = w >> 1, wc = w & 1;
  const int fr = l & 15, fk = (l >> 4) * 8;

  f32x4 acc[4][4] = {};

  for (int k0 = 0; k0 < K; k0 += 32) {
    __syncthreads();
#pragma unroll
    for (int p = 0; p < 2; ++p) {
      int c = p * 256 + tid;
      int row = c >> 2, col = (c & 3) * 8;
      *(short8*)(&As[c * 8]) = *(const short8*)(&A[(size_t)(m0 + row) * K + k0 + col]);
      *(short8*)(&Bs[c * 8]) = *(const short8*)(&Bt[(size_t)(n0 + row) * K + k0 + col]);
    }
    __syncthreads();
    short8 af[4], bf[4];
#pragma unroll
    for (int mi = 0; mi < 4; ++mi) af[mi] = *(const short8*)(&As[(wr * 64 + mi * 16 + fr) * 32 + fk]);
#pragma unroll
    for (int ni = 0; ni < 4; ++ni) bf[ni] = *(const short8*)(&Bs[(wc * 64 + ni * 16 + fr) * 32 + fk]);
#pragma unroll
    for (int mi = 0; mi < 4; ++mi)
#pragma unroll
      for (int ni = 0; ni < 4; ++ni)
        acc[mi][ni] = MFMA_BF16(af[mi], bf[ni], acc[mi][ni]);
  }

#pragma unroll
  for (int ni = 0; ni < 4; ++ni) {
    int col = n0 + wc * 64 + ni * 16 + fr;
    float bv = bias[col];
#pragma unroll
    for (int mi = 0; mi < 4; ++mi) {
#pragma unroll
      for (int q = 0; q < 4; ++q) {
        int row = m0 + wr * 64 + mi * 16 + (l >> 4) * 4 + q;
        C[(size_t)row * N + col] = acc[mi][ni][q] + bv;
      }
    }
  }
}

// ---------------- prep kernels (unchanged) ----------------
__global__ void prep_qkv_kernel(const float* __restrict__ qkv, const float* __restrict__ rwb,
                                const float* __restrict__ rrb,
                                ushort_t* __restrict__ qrw, ushort_t* __restrict__ qrr,
                                ushort_t* __restrict__ kb) {
  int idx = blockIdx.x * 256 + threadIdx.x;
  if (idx >= BATCH * NHEAD * T_LEN * DHEAD) return;
  int dd = idx & 63;
  int t = (idx >> 6) & 1023;
  int h = (idx >> 16) & 15;
  int b = idx >> 20;
  size_t src = (size_t)(t * BATCH + b) * (3 * EMB) + h * 64 + dd;
  float qv = qkv[src];
  float kv = qkv[src + EMB];
  qrw[idx] = f2bf(qv + rwb[h * 64 + dd]);
  qrr[idx] = f2bf(qv + rrb[h * 64 + dd]);
  kb[idx] = f2bf(kv);
}

__global__ void prep_vt_kernel(const float* __restrict__ qkv, ushort_t* __restrict__ vt) {
  __shared__ ushort_t tile[64][65];
  int bh = blockIdx.y;
  int b = bh >> 4, h = bh & 15;
  int t0 = blockIdx.x * 64;
  for (int i = threadIdx.x; i < 64 * 64; i += 256) {
    int r = i >> 6, c = i & 63;
    tile[r][c] = f2bf(qkv[(size_t)((t0 + r) * BATCH + b) * (3 * EMB) + 2 * EMB + h * 64 + c]);
  }
  __syncthreads();
  for (int i = threadIdx.x; i < 64 * 64; i += 256) {
    int dr = i >> 6, tc = i & 63;
    vt[(size_t)(bh * 64 + dr) * T_LEN + t0 + tc] = tile[tc][dr];
  }
}

__global__ void prep_rhp_kernel(const float* __restrict__ r_f, ushort_t* __restrict__ rhp) {
  int idx = blockIdx.x * 256 + threadIdx.x;
  if (idx >= NHEAD * 1152 * 64) return;
  int dd = idx & 63;
  int r6 = idx >> 6;
  int row = r6 % 1152;
  int h = r6 / 1152;
  int t = row - 64;
  ushort_t v = 0;
  if (t >= 0 && t < T_LEN) v = f2bf(r_f[(size_t)t * EMB + h * 64 + dd]);
  rhp[idx] = v;
}

// ---------------- fused rel-shift attention, flash-style online softmax ----------------
// Block: 32 q-rows x (b,h). 4 waves. ~5 KiB static LDS -> high occupancy.
// Wave roles: rhalf = w&1 (rows, both phases); ch = w>>1 (score col half / PV d half).
__global__ __launch_bounds__(256, 4)
void attn_kernel(const ushort_t* __restrict__ qrw, const ushort_t* __restrict__ qrr,
                 const ushort_t* __restrict__ kb, const ushort_t* __restrict__ vt,
                 const ushort_t* __restrict__ rhp, ushort_t* __restrict__ ctx) {
  __shared__ __attribute__((aligned(16))) char PtB[4096];  // P tile [32][64] bf16, XOR swizzled
  __shared__ float m_run[32], s_run[32], farr[32], mnewa[32];
  __shared__ float pmax[2][32], psum[2][32];

  const int tid = threadIdx.x, w = tid >> 6, l = tid & 63;
  const int bh = blockIdx.y, b = bh >> 4, h = bh & 15;
  const int i0 = blockIdx.x * 32;
  const int nkt = (i0 + 95) >> 6;
  const int fr = l & 15, fkq = (l >> 4) * 8;
  const int rhalf = w & 1;
  const int istrip_loc = 16 * rhalf;
  const int istrip = i0 + istrip_loc;
  const int ch = w >> 1;
  const int whalf = ch * 32;
  const int d0 = ch * 32;
  const float scale = 0.125f;

  // Q fragments in registers for the whole block
  short8 aqw[2], aqr[2];
  {
    size_t qb = ((size_t)bh * T_LEN + istrip + fr) * 64 + fkq;
    aqw[0] = *(const short8*)(qrw + qb);
    aqw[1] = *(const short8*)(qrw + qb + 32);
    aqr[0] = *(const short8*)(qrr + qb);
    aqr[1] = *(const short8*)(qrr + qb + 32);
  }

  if (tid < 32) { m_run[tid] = -3.0e38f; s_run[tid] = 0.f; }
  __syncthreads();

  f32x4 o0 = {0, 0, 0, 0}, o1 = {0, 0, 0, 0};
  const int arow = istrip_loc + fr;   // PV A-frag row (local)

  for (int jt = 0; jt < nkt; ++jt) {
    const int j0 = jt * 64;
    const int jc = j0 + whalf;

    // ---- phase A: scores for [16 rows][32 cols] quarter ----
    f32x4 ac0 = {0, 0, 0, 0}, ac1 = {0, 0, 0, 0};
    {
      size_t kb0 = ((size_t)bh * T_LEN + jc + fr) * 64 + fkq;
      short8 b0 = *(const short8*)(kb + kb0);
      short8 b1 = *(const short8*)(kb + kb0 + 32);
      ac0 = MFMA_BF16(aqw[0], b0, ac0);
      ac0 = MFMA_BF16(aqw[1], b1, ac0);
      size_t kb1 = kb0 + (size_t)16 * 64;
      short8 b2 = *(const short8*)(kb + kb1);
      short8 b3 = *(const short8*)(kb + kb1 + 32);
      ac1 = MFMA_BF16(aqw[0], b2, ac1);
      ac1 = MFMA_BF16(aqw[1], b3, ac1);
    }
    f32x4 pb0 = {0, 0, 0, 0}, pb1 = {0, 0, 0, 0}, pb2 = {0, 0, 0, 0};
    const int jr0 = T_LEN - 16 - istrip + jc;
    {
      size_t rb = ((size_t)h * 1152 + 64 + jr0 + fr) * 64 + fkq;
      short8 r0 = *(const short8*)(rhp + rb);
      short8 r1 = *(const short8*)(rhp + rb + 32);
      pb0 = MFMA_BF16(aqr[0], r0, pb0);
      pb0 = MFMA_BF16(aqr[1], r1, pb0);
      size_t rb1 = rb + (size_t)16 * 64;
      short8 r2 = *(const short8*)(rhp + rb1);
      short8 r3 = *(const short8*)(rhp + rb1 + 32);
      pb1 = MFMA_BF16(aqr[0], r2, pb1);
      pb1 = MFMA_BF16(aqr[1], r3, pb1);
      size_t rb2 = rb + (size_t)32 * 64;
      short8 r4 = *(const short8*)(rhp + rb2);
      short8 r5 = *(const short8*)(rhp + rb2 + 32);
      pb2 = MFMA_BF16(aqr[0], r4, pb2);
      pb2 = MFMA_BF16(aqr[1], r5, pb2);
    }
    float sreg[2][4];
#pragma unroll
    for (int ni = 0; ni < 2; ++ni) {
#pragma unroll
      for (int q = 0; q < 4; ++q) {
        int ri = 4 * (l >> 4) + q;
        int colp = 15 - ri + ni * 16 + fr;
        int src = (l & 48) | (colp & 15);
        float v0, v1;
        if (ni == 0) {
          v0 = __shfl(pb0[q], src, 64);
          v1 = __shfl(pb1[q], src, 64);
        } else {
          v0 = __shfl(pb1[q], src, 64);
          v1 = __shfl(pb2[q], src, 64);
        }
        float pv = ((colp >> 4) == ni) ? v0 : v1;
        float accv = (ni == 0) ? ac0[q] : ac1[q];
        float s = (accv + pv) * scale;
        int ig = istrip + ri;
        int jg = jc + ni * 16 + fr;
        if (jg > ig) s = -1e9f;
        sreg[ni][q] = s;
      }
    }
    // per-row max over this wave's 32 cols
#pragma unroll
    for (int q = 0; q < 4; ++q) {
      float mq = fmaxf(sreg[0][q], sreg[1][q]);
#pragma unroll
      for (int o = 8; o; o >>= 1) mq = fmaxf(mq, __shfl_xor(mq, o, 64));
      if (fr == 0) pmax[ch][istrip_loc + 4 * (l >> 4) + q] = mq;
    }
    __syncthreads();

    // ---- phase B: combine maxes, P = exp(s - m_new) -> Pt (bf16, swizzled), row sums ----
    if (w == 0 && l < 32) {
      float mo = m_run[l];
      float mn = fmaxf(mo, fmaxf(pmax[0][l], pmax[1][l]));
      farr[l] = __expf(mo - mn);
      mnewa[l] = mn;
    }
#pragma unroll
    for (int q = 0; q < 4; ++q) {
      int rl = istrip_loc + 4 * (l >> 4) + q;
      float mn = fmaxf(m_run[rl], fmaxf(pmax[0][rl], pmax[1][rl]));
      float p0 = __expf(sreg[0][q] - mn);
      float p1 = __expf(sreg[1][q] - mn);
      int cA = whalf + fr, cB = whalf + 16 + fr;
      *(ushort_t*)(PtB + ((rl * 128 + cA * 2) ^ ((rl & 7) << 4))) = f2bf(p0);
      *(ushort_t*)(PtB + ((rl * 128 + cB * 2) ^ ((rl & 7) << 4))) = f2bf(p1);
      float sq = p0 + p1;
#pragma unroll
      for (int o = 8; o; o >>= 1) sq += __shfl_xor(sq, o, 64);
      if (fr == 0) psum[ch][rl] = sq;
    }
    __syncthreads();

    // ---- phase C: rescale O, PV MFMA; wave0 updates running stats ----
    {
#pragma unroll
      for (int q = 0; q < 4; ++q) {
        float fq = farr[istrip_loc + 4 * (l >> 4) + q];
        o0[q] *= fq;
        o1[q] *= fq;
      }
    }
#pragma unroll
    for (int ks = 0; ks < 2; ++ks) {
      int colb = ks * 32 + fkq;
      short8 pa = *(const short8*)(PtB + ((arow * 128 + colb * 2) ^ ((arow & 7) << 4)));
      size_t vb = ((size_t)bh * 64 + d0 + fr) * T_LEN + j0 + colb;
      short8 v0 = *(const short8*)(vt + vb);
      short8 v1 = *(const short8*)(vt + vb + (size_t)16 * T_LEN);
      o0 = MFMA_BF16(pa, v0, o0);
      o1 = MFMA_BF16(pa, v1, o1);
    }
    if (w == 0 && l < 32) {
      s_run[l] = s_run[l] * farr[l] + psum[0][l] + psum[1][l];
      m_run[l] = mnewa[l];
    }
  }
  __syncthreads();

  // ---- epilogue: normalize, write ctx [T][B][E] bf16 ----
#pragma unroll
  for (int ni = 0; ni < 2; ++ni) {
#pragma unroll
    for (int q = 0; q < 4; ++q) {
      int rloc = istrip_loc + 4 * (l >> 4) + q;
      int ig = i0 + rloc;
      int dd = d0 + ni * 16 + fr;
      float val = ((ni == 0) ? o0[q] : o1[q]) / s_run[rloc];
      ctx[((size_t)ig * BATCH + b) * EMB + h * 64 + dd] = f2bf(val);
    }
  }
}

// ---------------- launch ----------------
extern "C" void kernel_launch(void* const* d_in, const int* in_sizes, int n_in,
                              void* d_out, int out_size, void* d_ws, size_t ws_size,
                              hipStream_t stream) {
  (void)in_sizes; (void)n_in; (void)out_size; (void)ws_size;
  const float* x = (const float*)d_in[0];
  const float* pos = (const float*)d_in[1];
  const float* in_w_mu = (const float*)d_in[3];
  const float* in_w_rho = (const float*)d_in[4];
  const float* in_w_eps = (const float*)d_in[5];
  const float* in_b_mu = (const float*)d_in[6];
  const float* in_b_rho = (const float*)d_in[7];
  const float* in_b_eps = (const float*)d_in[8];
  const float* pos_w_mu = (const float*)d_in[9];
  const float* pos_w_rho = (const float*)d_in[10];
  const float* pos_w_eps = (const float*)d_in[11];
  const float* pos_b_mu = (const float*)d_in[12];
  const float* pos_b_rho = (const float*)d_in[13];
  const float* pos_b_eps = (const float*)d_in[14];
  const float* out_w_mu = (const float*)d_in[15];
  const float* out_w_rho = (const float*)d_in[16];
  const float* out_w_eps = (const float*)d_in[17];
  const float* out_b_mu = (const float*)d_in[18];
  const float* out_b_rho = (const float*)d_in[19];
  const float* out_b_eps = (const float*)d_in[20];
  const float* rw_mu = (const float*)d_in[21];
  const float* rw_rho = (const float*)d_in[22];
  const float* rw_eps = (const float*)d_in[23];
  const float* rr_mu = (const float*)d_in[24];
  const float* rr_rho = (const float*)d_in[25];
  const float* rr_eps = (const float*)d_in[26];

  char* ws = (char*)d_ws;
  ushort_t* in_w_bf  = (ushort_t*)(ws + 0);
  ushort_t* pos_w_bf = (ushort_t*)(ws + 6291456);
  ushort_t* out_w_bf = (ushort_t*)(ws + 8388608);
  float* in_b  = (float*)(ws + 10485760);
  float* pos_b = (float*)(ws + 10498048);
  float* out_b = (float*)(ws + 10502144);
  float* rwb   = (float*)(ws + 10506240);
  float* rrb   = (float*)(ws + 10510336);
  ushort_t* x_bf    = (ushort_t*)(ws + 10514432);
  ushort_t* posx_bf = (ushort_t*)(ws + 18903040);
  float* qkv_f = (float*)(ws + 21000192);
  float* r_f   = (float*)(ws + 71331840);
  ushort_t* qrw = (ushort_t*)(ws + 75526144);
  ushort_t* qrr = (ushort_t*)(ws + 83914752);
  ushort_t* kb  = (ushort_t*)(ws + 92303360);
  ushort_t* vt  = (ushort_t*)(ws + 100691968);
  ushort_t* rhp = (ushort_t*)(ws + 109080576);
  ushort_t* ctx = (ushort_t*)(ws + 21000192);  // alias qkv_f (dead after prep)

  sample_bf16_kernel<<<12288, 256, 0, stream>>>(in_w_mu, in_w_rho, in_w_eps, in_w_bf, 3145728);
  sample_bf16_kernel<<<4096, 256, 0, stream>>>(pos_w_mu, pos_w_rho, pos_w_eps, pos_w_bf, 1048576);
  sample_bf16_kernel<<<4096, 256, 0, stream>>>(out_w_mu, out_w_rho, out_w_eps, out_w_bf, 1048576);
  sample_f32_kernel<<<12, 256, 0, stream>>>(in_b_mu, in_b_rho, in_b_eps, in_b, 3072);
  sample_f32_kernel<<<4, 256, 0, stream>>>(pos_b_mu, pos_b_rho, pos_b_eps, pos_b, 1024);
  sample_f32_kernel<<<4, 256, 0, stream>>>(out_b_mu, out_b_rho, out_b_eps, out_b, 1024);
  sample_f32_kernel<<<4, 256, 0, stream>>>(rw_mu, rw_rho, rw_eps, rwb, 1024);
  sample_f32_kernel<<<4, 256, 0, stream>>>(rr_mu, rr_rho, rr_eps, rrb, 1024);
  cast_bf16_kernel<<<16384, 256, 0, stream>>>(x, x_bf, 4194304);
  cast_bf16_kernel<<<4096, 256, 0, stream>>>(pos, posx_bf, 1048576);

  gemm_bt_kernel<<<dim3(32, 24), 256, 0, stream>>>(x_bf, in_w_bf, in_b, qkv_f, 4096, 3072, 1024);
  gemm_bt_kernel<<<dim3(8, 8), 256, 0, stream>>>(posx_bf, pos_w_bf, pos_b, r_f, 1024, 1024, 1024);

  prep_qkv_kernel<<<16384, 256, 0, stream>>>(qkv_f, rwb, rrb, qrw, qrr, kb);
  prep_vt_kernel<<<dim3(16, 64), 256, 0, stream>>>(qkv_f, vt);
  prep_rhp_kernel<<<4608, 256, 0, stream>>>(r_f, rhp);

  attn_kernel<<<dim3(32, 64), 256, 0, stream>>>(qrw, qrr, kb, vt, rhp, ctx);

  gemm_bt_kernel<<<dim3(32, 8), 256, 0, stream>>>(ctx, out_w_bf, out_b, (float*)d_out, 4096, 1024, 1024);
}